// Round 17
// baseline (142.980 us; speedup 1.0000x reference)
//
#include <hip/hip_runtime.h>
#include <hip/hip_bf16.h>

// Problem constants
#define B_ 2
#define S_ 1024
#define I_ 512
#define C_ 32
#define EPS_ 1e-5f

// ---------------------------------------------------------------------------
// a_t/b_t layout (fp8 e4m3, BYTE strides): [b][sg][ig][i_l][c][s64]
//   s64: 64 B contiguous; c: stride 64 B -> wave block 2 KB contiguous
//   i_l: ILST=2064 B (2048 used + 16 pad, non-pow2), ig: 4*ILST,
//   sg: 128*IGST, b: 16*SGST.  Total per array ~33.8 MB.
// ---------------------------------------------------------------------------
#define ILST 2064
#define IGST (4 * ILST)            // 8256 B
#define SGST (128 * IGST)          // 1,056,768 B
#define BST  (16 * SGST)           // 16,908,288 B

// GEMM tiling: 256x256 tile, 8 waves, BK=32, double-buffered.
#define GBM 256
#define GBN 256
#define BK 32
#define NT (S_ / BK)   // 32 K-steps

typedef __attribute__((ext_vector_type(8))) short bf16x8;   // 8 bf16 (MFMA bf16 A/B frag)
typedef __attribute__((ext_vector_type(4))) short bf16x4;
typedef __attribute__((ext_vector_type(4))) float f32x4;    // MFMA C/D frag
typedef __attribute__((ext_vector_type(2))) int  i32x2;     // 8 B

static __device__ __forceinline__ short f2bf(float f) {
    union { __hip_bfloat16 h; short s; } u;
    u.h = __float2bfloat16(f);
    return u.s;
}
static __device__ __forceinline__ float bf2f(short s) {
    union { float f; unsigned u; } u;
    u.u = ((unsigned)(unsigned short)s) << 16;
    return u.f;
}

// ---------------------------------------------------------------------------
// Pass 0 (v17): WIDE-READ blocks. Block covers 16 i x 64 s (4x v16): read
// runs grow 512B -> 2KB (the one mechanism that ever moved this kernel,
// r13's coalescing). Four wave-private 16-KB frag-linear regions (region r
// holds i_lr in [4r,4r+4)); stage maps (sc,i_lr,slot) directly into region
// [i_lr>>2] with XOR keys (i2<<5) ^ ((ks&3)<<4) — bank-audited to the
// volume floor for stage-writes, row reads/writes, and af reads. Wave w
// computes region w: 64 MFMAs, acc-diet, fp8 pack, 512B-contiguous stores.
// Weights amortized 4x. LDS 74.8 KB -> 2 blocks/CU (occupancy proven
// irrelevant rounds 8-12).
// ---------------------------------------------------------------------------
__global__ __launch_bounds__(256) void ln_proj_kernel(
    const float* __restrict__ m,
    const float* __restrict__ g, const float* __restrict__ beta,
    const float* __restrict__ Wa, const float* __restrict__ ba,
    const float* __restrict__ Wb, const float* __restrict__ bb,
    char* __restrict__ a_t, char* __restrict__ b_t)
{
    __shared__ __align__(16) __hip_bfloat16 mhf[4 * 8192];   // 64 KiB: 4 frag-linear regions
    __shared__ __align__(16) char trb[4 * 2304];             // 9 KiB fp8 transpose (wave-private)

    const int tid  = threadIdx.x;
    const int lane = tid & 63;
    const int w    = tid >> 6;
    const int lo   = lane & 15;
    const int hi   = lane >> 4;

    const int blk = blockIdx.x;                 // ((b*16 + sg)*32 + ig2), ig2 fastest
    const int ig2 = blk & 31;                   // 16-i group
    const int sg  = (blk >> 5) & 15;
    const int b   = blk >> 9;
    const int s0  = sg * 64;
    const int i0  = ig2 * 16;

    const int i_l = tid & 3;
    const int s_l = tid >> 2;

    // ---- B-frags: Wa/Wb rows as bf16x8 (lane l: W[c=(f&1)*16+lo][k=hi*8+e]) ----
    bf16x8 bw[4];
    float biasv[4];
#pragma unroll
    for (int f = 0; f < 4; ++f) {
        const float* Wsrc = (f & 2) ? Wb : Wa;
        const float* bsrc = (f & 2) ? bb : ba;
        int c = (f & 1) * 16 + lo;
        const float* src = Wsrc + c * C_ + hi * 8;
        float4 u0 = *reinterpret_cast<const float4*>(src);
        float4 u1 = *reinterpret_cast<const float4*>(src + 4);
        bf16x8 ch;
        ch[0] = f2bf(u0.x); ch[1] = f2bf(u0.y); ch[2] = f2bf(u0.z); ch[3] = f2bf(u0.w);
        ch[4] = f2bf(u1.x); ch[5] = f2bf(u1.y); ch[6] = f2bf(u1.z); ch[7] = f2bf(u1.w);
        bw[f] = ch;
        biasv[f] = bsrc[c];
    }

    char* ldsb = reinterpret_cast<char*>(mhf);

    // ---- Phase 1: coalesced stage (64 s-chunks x 2KB dense runs) ----
    // g4 = float4 index; sc = s-chunk (128 float4 each); rem = i_lr*8 + slot.
    // dest: region = i_lr>>2 (16-KB offset), i2 = i_lr&3, pt = i2*4 + (sc>>4);
    // byte = (pt*1024 + (slot>>1)*256 + (sc&15)*16 + (slot&1)*8)
    //        ^ (i2<<5) ^ (((slot>>1)&3)<<4).  Bank audit: 16 keys x 4 = floor.
    const float* mb = m + ((size_t)(b * S_ + s0) * I_ + i0) * C_;
#pragma unroll
    for (int it = 0; it < 32; ++it) {
        int g4   = it * 256 + tid;              // 0..8191
        int sc   = g4 >> 7;                     // s chunk 0..63
        int rem  = g4 & 127;                    // i_lr*8 + slot
        int i_lr = rem >> 3;                    // 0..15
        int slot = rem & 7;
        float4 v = *reinterpret_cast<const float4*>(
            mb + (size_t)sc * (I_ * C_) + rem * 4);
        bf16x4 pk;
        pk[0] = f2bf(v.x); pk[1] = f2bf(v.y); pk[2] = f2bf(v.z); pk[3] = f2bf(v.w);
        int i2   = i_lr & 3;
        int ks   = slot >> 1;
        int pt   = i2 * 4 + (sc >> 4);
        int byte = (i_lr >> 2) * 16384
                 + ((pt * 1024 + ks * 256 + (sc & 15) * 16 + (slot & 1) * 8)
                    ^ (i2 << 5) ^ ((ks & 3) << 4));
        *reinterpret_cast<bf16x4*>(ldsb + byte) = pk;
    }
    __syncthreads();

    // ---- Phase 2: in-place LN, 4 rows/thread (one per region) ----
    const int pt2  = i_l * 4 + (s_l >> 4);
    const int rb   = pt2 * 1024 + (s_l & 15) * 16;
#pragma unroll
    for (int r = 0; r < 4; ++r) {
        bf16x8 ch[4];
#pragma unroll
        for (int ks = 0; ks < 4; ++ks)
            ch[ks] = *reinterpret_cast<const bf16x8*>(
                ldsb + r * 16384 + ((rb + ks * 256) ^ (i_l << 5) ^ ((ks & 3) << 4)));

        float x[C_];
#pragma unroll
        for (int ks = 0; ks < 4; ++ks)
#pragma unroll
            for (int e = 0; e < 8; ++e) x[ks * 8 + e] = bf2f(ch[ks][e]);

        float mu = 0.f;
#pragma unroll
        for (int c = 0; c < C_; ++c) mu += x[c];
        mu *= (1.f / C_);
        float var = 0.f;
#pragma unroll
        for (int c = 0; c < C_; ++c) { float dd = x[c] - mu; var += dd * dd; }
        float rs = rsqrtf(var * (1.f / C_) + EPS_);
#pragma unroll
        for (int c = 0; c < C_; ++c) x[c] = (x[c] - mu) * rs * g[c] + beta[c];

#pragma unroll
        for (int ks = 0; ks < 4; ++ks) {
            bf16x8 cw;
#pragma unroll
            for (int e = 0; e < 8; ++e) cw[e] = f2bf(x[ks * 8 + e]);
            *reinterpret_cast<bf16x8*>(
                ldsb + r * 16384 + ((rb + ks * 256) ^ (i_l << 5) ^ ((ks & 3) << 4))) = cw;
        }
    }
    __syncthreads();   // normalized regions visible block-wide

    // ---- A-frag reads: wave w reads ALL 16 pt of region w ----
    // frag 16B for lane: ks = hi (const/lane), so key2 = hi<<4.
    bf16x8 af[16];
#pragma unroll
    for (int pt = 0; pt < 16; ++pt) {
        int byte = w * 16384
                 + ((pt * 1024 + lane * 16) ^ ((pt >> 2) << 5) ^ (hi << 4));
        af[pt] = *reinterpret_cast<const bf16x8*>(ldsb + byte);
    }

    // ---- per-i2 p-loop: 2 MFMAs live at a time, fp8 pack, 512B stores ----
    char* trw = trb + w * 2304;   // wave-private 2304 B
#pragma unroll
    for (int i2 = 0; i2 < 4; ++i2) {
        const size_t wbase = (size_t)b * BST + (size_t)sg * SGST
                           + (size_t)(ig2 * 4 + w) * IGST + (size_t)i2 * ILST;
#pragma unroll
        for (int p = 0; p < 2; ++p) {
#pragma unroll
            for (int q = 0; q < 4; ++q) {
#pragma unroll
                for (int fh = 0; fh < 2; ++fh) {
                    int f = p * 2 + fh;
                    f32x4 d = __builtin_amdgcn_mfma_f32_16x16x32_bf16(
                        af[i2 * 4 + q], bw[f], (f32x4){0.f, 0.f, 0.f, 0.f}, 0, 0, 0);
                    int pk = __builtin_amdgcn_cvt_pk_fp8_f32(d[0] + biasv[f], d[1] + biasv[f], 0, false);
                    pk     = __builtin_amdgcn_cvt_pk_fp8_f32(d[2] + biasv[f], d[3] + biasv[f], pk, true);
                    int c = fh * 16 + lo;
                    int s = q * 16 + hi * 4;
                    *reinterpret_cast<int*>(trw + c * 72 + s) = pk;
                }
            }
            asm volatile("" ::: "memory");   // trw writes before reads
            char* outp = p ? b_t : a_t;
#pragma unroll
            for (int cg = 0; cg < 4; ++cg) {
                int c  = cg * 8 + (lane >> 3);
                int s8 = (lane & 7) * 8;
                i32x2 vv = *reinterpret_cast<const i32x2*>(trw + c * 72 + s8);
                *reinterpret_cast<i32x2*>(outp + wbase + cg * 512 + lane * 8) = vv;
            }
            asm volatile("" ::: "memory");   // reads before next overwrite
        }
    }
}

// ---------------------------------------------------------------------------
// Pass 1 (unchanged v15/v16): fp8 GEMM. 64 independent GEMMs, 256x256 tiles,
// 8 waves, BK=32 dbuf. Rows are 32 B -> dense 512-B frag windows, no
// swizzle needed. mfma_f32_16x16x32_fp8_fp8. T1 XCD swizzle; epilogue
// folds 1/S, stores bf16.
// ---------------------------------------------------------------------------
__global__ __launch_bounds__(512, 2) void opm_gemm_kernel(
    const char* __restrict__ a_t,
    const char* __restrict__ b_t,
    __hip_bfloat16* __restrict__ outer)
{
    __shared__ __align__(16) char sA[2][GBM * BK];  // 8 KiB per buf
    __shared__ __align__(16) char sB[2][GBN * BK];  // total 32 KiB

    const int tid  = threadIdx.x;
    const int wave = tid >> 6;           // 0..7
    const int lane = tid & 63;
    // T1: 256 blocks % 8 == 0 -> bijective chunked swizzle (32 blocks/XCD)
    const int swz  = (blockIdx.x & 7) * 32 + (blockIdx.x >> 3);
    const int bc   = swz >> 2;           // (b*C + c), 0..63
    const int tile = swz & 3;            // 2x2 output tiles per GEMM
    const int i0   = (tile >> 1) * GBM;
    const int j0   = (tile & 1)  * GBN;

    const char* Ap = a_t + (size_t)(bc >> 5) * BST + (size_t)(bc & 31) * 64
                         + (size_t)(i0 >> 2) * IGST;
    const char* Bp = b_t + (size_t)(bc >> 5) * BST + (size_t)(bc & 31) * 64
                         + (size_t)(j0 >> 2) * IGST;

    f32x4 acc[8][4];
#pragma unroll
    for (int mI = 0; mI < 8; ++mI)
#pragma unroll
        for (int nI = 0; nI < 4; ++nI)
            acc[mI][nI] = (f32x4){0.f, 0.f, 0.f, 0.f};

    const int wr = wave >> 2;      // wave row (0..1): rows [wr*128, +128)
    const int wc = wave & 3;       // wave col (0..3): cols [wc*64, +64)
    const int half = lane >> 4;    // k-group (k = half*8 + e)
    const int lrow = lane & 15;

    // staging: thread -> (row = tid>>1, 16B-half = tid&1); LDS dest linear
    const int row_me = tid >> 1;                       // 0..255
    const size_t rowoff = (size_t)(row_me >> 2) * IGST + (size_t)(row_me & 3) * ILST
                        + (size_t)(tid & 1) * 16;

#define STAGE(bufidx, t) do {                                                              \
        const size_t sgo = (size_t)((t) >> 1) * SGST;                                      \
        const int    sho = ((t) & 1) * 32;                                                 \
        const char* gA0 = Ap + sgo + rowoff + sho;                                         \
        const char* gB0 = Bp + sgo + rowoff + sho;                                         \
        char* lA = (char*)(&sA[bufidx][0]) + tid * 16;                                     \
        char* lB = (char*)(&sB[bufidx][0]) + tid * 16;                                     \
        __builtin_amdgcn_global_load_lds((const __attribute__((address_space(1))) void*)gA0,      \
                                         (__attribute__((address_space(3))) void*)lA, 16, 0, 0);  \
        __builtin_amdgcn_global_load_lds((const __attribute__((address_space(1))) void*)gB0,      \
                                         (__attribute__((address_space(3))) void*)lB, 16, 0, 0);  \
    } while (0)

    STAGE(0, 0);
    asm volatile("s_waitcnt vmcnt(0)" ::: "memory");
    __syncthreads();

#pragma unroll 2
    for (int t = 0; t < NT; ++t) {
        const int cur = t & 1;
        if (t + 1 < NT) STAGE(cur ^ 1, t + 1);   // prefetch next K-slab

        const char* lA = &sA[cur][0];
        const char* lB = &sB[cur][0];
        long aF[8], bF[4];
#pragma unroll
        for (int mI = 0; mI < 8; ++mI) {
            int row = wr * 128 + mI * 16 + lrow;
            aF[mI] = *reinterpret_cast<const long*>(lA + row * 32 + half * 8);
        }
#pragma unroll
        for (int nI = 0; nI < 4; ++nI) {
            int row = wc * 64 + nI * 16 + lrow;
            bF[nI] = *reinterpret_cast<const long*>(lB + row * 32 + half * 8);
        }
#pragma unroll
        for (int mI = 0; mI < 8; ++mI)
#pragma unroll
            for (int nI = 0; nI < 4; ++nI)
                acc[mI][nI] = __builtin_amdgcn_mfma_f32_16x16x32_fp8_fp8(
                    aF[mI], bF[nI], acc[mI][nI], 0, 0, 0);

        __syncthreads();   // drains vmcnt+lgkmcnt (buffers safe to swap)
    }
#undef STAGE

    // C/D layout (dtype-independent): col = lane&15, row = (lane>>4)*4 + reg
    __hip_bfloat16* Op = outer + (size_t)bc * (I_ * I_);
#pragma unroll
    for (int mI = 0; mI < 8; ++mI) {
        int ii = i0 + wr * 128 + mI * 16 + half * 4;
#pragma unroll
        for (int nI = 0; nI < 4; ++nI) {
            int jj = j0 + wc * 64 + nI * 16 + lrow;
#pragma unroll
            for (int r = 0; r < 4; ++r)
                Op[(size_t)(ii + r) * I_ + jj] =
                    __float2bfloat16(acc[mI][nI][r] * (1.f / S_));
        }
    }
}

// ---------------------------------------------------------------------------
// Pass 2: out[b,i,j,c] = bo[c] + sum_c' Wo[c,c'] * outer_scaled[(b,c'),i,j]
// ---------------------------------------------------------------------------
__global__ __launch_bounds__(256) void wo_kernel(
    const __hip_bfloat16* __restrict__ outer,
    const float* __restrict__ Wo, const float* __restrict__ bo,
    float* __restrict__ out)
{
    int tid = blockIdx.x * 256 + threadIdx.x;   // ((b*I + i)*J + j)
    int j  = tid & (I_ - 1);
    int bi = tid >> 9;
    int i  = bi & (I_ - 1);
    int b  = bi >> 9;

    const __hip_bfloat16* ip = outer + ((size_t)(b * C_) * I_ + i) * I_ + j;
    float v[C_];
#pragma unroll
    for (int c = 0; c < C_; ++c) v[c] = __bfloat162float(ip[(size_t)c * (I_ * I_)]);

    float o[C_];
#pragma unroll
    for (int c = 0; c < C_; ++c) {
        float acc = bo[c];
#pragma unroll
        for (int k = 0; k < C_; ++k) acc = fmaf(Wo[c * C_ + k], v[k], acc);
        o[c] = acc;
    }

    float* op = out + (size_t)tid * C_;
#pragma unroll
    for (int vv = 0; vv < 8; ++vv) {
        float4 t4 = { o[4*vv+0], o[4*vv+1], o[4*vv+2], o[4*vv+3] };
        reinterpret_cast<float4*>(op)[vv] = t4;
    }
}

// ---------------------------------------------------------------------------
extern "C" void kernel_launch(void* const* d_in, const int* in_sizes, int n_in,
                              void* d_out, int out_size, void* d_ws, size_t ws_size,
                              hipStream_t stream) {
    const float* m    = (const float*)d_in[0];
    const float* ln_g = (const float*)d_in[1];
    const float* ln_b = (const float*)d_in[2];
    const float* Wa   = (const float*)d_in[3];
    const float* ba   = (const float*)d_in[4];
    const float* Wb   = (const float*)d_in[5];
    const float* bb   = (const float*)d_in[6];
    const float* Wo   = (const float*)d_in[7];
    const float* bo   = (const float*)d_in[8];
    float* out = (float*)d_out;

    const size_t ABYTES = (size_t)B_ * BST;          // fp8 bytes per array (~33.8 MB)
    const size_t nO  = (size_t)B_ * C_ * I_ * I_;    // outer elems (32 MiB bf16)
    const size_t need = ABYTES * 2 + nO * sizeof(__hip_bfloat16);  // ~100 MB
    if (ws_size < need) return;   // diagnostic: output stays zero -> ws too small

    char* a_t = (char*)d_ws;
    char* b_t = a_t + ABYTES;
    __hip_bfloat16* outer = (__hip_bfloat16*)(b_t + ABYTES);

    ln_proj_kernel<<<B_ * 16 * 32, 256, 0, stream>>>(m, ln_g, ln_b, Wa, ba, Wb, bb, a_t, b_t);
    opm_gemm_kernel<<<B_ * C_ * 4, 512, 0, stream>>>(a_t, b_t, outer);
    wo_kernel<<<(B_ * I_ * I_) / 256, 256, 0, stream>>>(outer, Wo, bo, out);
}

// Round 18
// 130.357 us; speedup vs baseline: 1.0968x; 1.0968x over previous
//
#include <hip/hip_runtime.h>
#include <hip/hip_bf16.h>

// Problem constants
#define B_ 2
#define S_ 1024
#define I_ 512
#define C_ 32
#define EPS_ 1e-5f

// ---------------------------------------------------------------------------
// a_t/b_t layout (fp8 e4m3, BYTE strides): [b][sg][ig][i_l][c][s64]
//   s64: 64 B contiguous; c: stride 64 B -> wave block 2 KB contiguous
//   i_l: ILST=2064 B (2048 used + 16 pad, non-pow2), ig: 4*ILST,
//   sg: 128*IGST, b: 16*SGST.  Total per array ~33.8 MB.
// ---------------------------------------------------------------------------
#define ILST 2064
#define IGST (4 * ILST)            // 8256 B
#define SGST (128 * IGST)          // 1,056,768 B
#define BST  (16 * SGST)           // 16,908,288 B

// GEMM tiling: 256x256 tile, 8 waves, BK=32, double-buffered.
#define GBM 256
#define GBN 256
#define BK 32
#define NT (S_ / BK)   // 32 K-steps

typedef __attribute__((ext_vector_type(8))) short bf16x8;   // 8 bf16 (MFMA bf16 A/B frag)
typedef __attribute__((ext_vector_type(4))) short bf16x4;
typedef __attribute__((ext_vector_type(4))) float f32x4;    // MFMA C/D frag
typedef __attribute__((ext_vector_type(2))) int  i32x2;     // 8 B

static __device__ __forceinline__ short f2bf(float f) {
    union { __hip_bfloat16 h; short s; } u;
    u.h = __float2bfloat16(f);
    return u.s;
}
static __device__ __forceinline__ float bf2f(short s) {
    union { float f; unsigned u; } u;
    u.u = ((unsigned)(unsigned short)s) << 16;
    return u.f;
}

// ---------------------------------------------------------------------------
// Pass 0 (v18 = v16 revert — best verified: 130.05 us total).
// v17's wide-read blocks regressed (143 us): at 2 blocks/CU the longer
// per-wave phase chains cost more than the 2-KB read runs gained.
//
// v16: single-buffer staging — raw m staged (as bf16) DIRECTLY into the
// swizzled frag-linear mhf layout; LN in-place (read own row, normalize in
// regs, write back). LDS 25.6 KB, 2 barriers, coalesced 512-B read runs,
// bf16 MFMA projection, fp8 e4m3 output, 512-B contiguous wave-stores.
// ---------------------------------------------------------------------------
__global__ __launch_bounds__(256) void ln_proj_kernel(
    const float* __restrict__ m,
    const float* __restrict__ g, const float* __restrict__ beta,
    const float* __restrict__ Wa, const float* __restrict__ ba,
    const float* __restrict__ Wb, const float* __restrict__ bb,
    char* __restrict__ a_t, char* __restrict__ b_t)
{
    __shared__ __align__(16) __hip_bfloat16 mhf[8192];   // 16 KiB frag-linear mh
    __shared__ __align__(16) char trb[4 * 2304];         // 9 KiB fp8 transpose (wave-private)

    const int tid  = threadIdx.x;
    const int lane = tid & 63;
    const int w    = tid >> 6;
    const int lo   = lane & 15;
    const int hi   = lane >> 4;

    const int blk = blockIdx.x;                 // ((b*16 + sg)*128 + ig), ig fastest
    const int ig = blk & 127;
    const int sg = (blk >> 7) & 15;
    const int b  = blk >> 11;
    const int s0 = sg * 64;
    const int i0 = ig * 4;

    const int i_l = tid & 3;
    const int s_l = tid >> 2;

    // ---- B-frags: Wa/Wb rows as bf16x8 (lane l: W[c=(f&1)*16+lo][k=hi*8+e]) ----
    bf16x8 bw[4];
    float biasv[4];
#pragma unroll
    for (int f = 0; f < 4; ++f) {
        const float* Wsrc = (f & 2) ? Wb : Wa;
        const float* bsrc = (f & 2) ? bb : ba;
        int c = (f & 1) * 16 + lo;
        const float* src = Wsrc + c * C_ + hi * 8;
        float4 u0 = *reinterpret_cast<const float4*>(src);
        float4 u1 = *reinterpret_cast<const float4*>(src + 4);
        bf16x8 ch;
        ch[0] = f2bf(u0.x); ch[1] = f2bf(u0.y); ch[2] = f2bf(u0.z); ch[3] = f2bf(u0.w);
        ch[4] = f2bf(u1.x); ch[5] = f2bf(u1.y); ch[6] = f2bf(u1.z); ch[7] = f2bf(u1.w);
        bw[f] = ch;
        biasv[f] = bsrc[c];
    }

    char* ldsb = reinterpret_cast<char*>(mhf);

    // ---- Phase 1: coalesced stage of raw m (bf16) DIRECTLY frag-linear ----
    const float* mb = m + ((size_t)(b * S_ + s0) * I_ + i0) * C_;
#pragma unroll
    for (int it = 0; it < 8; ++it) {
        int g4   = it * 256 + tid;              // float4 index 0..2047
        int sc   = g4 >> 5;                     // s chunk 0..63
        int rem  = g4 & 31;                     // i_lr*8 + slot
        int i_lr = rem >> 3;
        int slot = rem & 7;
        float4 v = *reinterpret_cast<const float4*>(
            mb + (size_t)sc * (I_ * C_) + rem * 4);
        bf16x4 pk;
        pk[0] = f2bf(v.x); pk[1] = f2bf(v.y); pk[2] = f2bf(v.z); pk[3] = f2bf(v.w);
        int pt   = i_lr * 4 + (sc >> 4);
        int byte = (pt * 1024 + (slot >> 1) * 256 + (sc & 15) * 16 + (slot & 1) * 8)
                   ^ (i_lr << 5);
        *reinterpret_cast<bf16x4*>(ldsb + byte) = pk;
    }
    __syncthreads();

    // ---- Phase 2: in-place LN — read own row (4x b128), normalize, write back ----
    const int pt2  = i_l * 4 + (s_l >> 4);
    const int base = pt2 * 1024 + (s_l & 15) * 16;
    const int swz2 = (i_l & 3) << 5;
    bf16x8 ch[4];
#pragma unroll
    for (int ks = 0; ks < 4; ++ks)
        ch[ks] = *reinterpret_cast<const bf16x8*>(ldsb + ((base + ks * 256) ^ swz2));

    float x[C_];
#pragma unroll
    for (int ks = 0; ks < 4; ++ks)
#pragma unroll
        for (int e = 0; e < 8; ++e) x[ks * 8 + e] = bf2f(ch[ks][e]);

    float mu = 0.f;
#pragma unroll
    for (int c = 0; c < C_; ++c) mu += x[c];
    mu *= (1.f / C_);
    float var = 0.f;
#pragma unroll
    for (int c = 0; c < C_; ++c) { float dd = x[c] - mu; var += dd * dd; }
    float rs = rsqrtf(var * (1.f / C_) + EPS_);
#pragma unroll
    for (int c = 0; c < C_; ++c) x[c] = (x[c] - mu) * rs * g[c] + beta[c];

#pragma unroll
    for (int ks = 0; ks < 4; ++ks) {
        bf16x8 cw;
#pragma unroll
        for (int e = 0; e < 8; ++e) cw[e] = f2bf(x[ks * 8 + e]);
        *reinterpret_cast<bf16x8*>(ldsb + ((base + ks * 256) ^ swz2)) = cw;
    }
    __syncthreads();   // normalized mhf visible block-wide

    // ---- A-frag reads (XOR wave-uniform: pt = w*4+q -> pt>>2 = w) ----
    bf16x8 af[4];
#pragma unroll
    for (int q = 0; q < 4; ++q) {
        int pt   = w * 4 + q;
        int byte = (pt * 1024 + lane * 16) ^ ((pt >> 2) << 5);
        af[q] = *reinterpret_cast<const bf16x8*>(ldsb + byte);
    }

    // ---- p-loop: bf16 MFMA, bias, FP8 pack, transpose (trb separate),
    //      contiguous 512B wave-stores. Fences order trw write->read phases.
    char* trw = trb + w * 2304;   // wave-private 2304 B
    const size_t wbase = (size_t)b * BST + (size_t)sg * SGST
                       + (size_t)ig * IGST + (size_t)w * ILST;
#pragma unroll
    for (int p = 0; p < 2; ++p) {
#pragma unroll
        for (int q = 0; q < 4; ++q) {
#pragma unroll
            for (int fh = 0; fh < 2; ++fh) {
                int f = p * 2 + fh;
                f32x4 d = __builtin_amdgcn_mfma_f32_16x16x32_bf16(
                    af[q], bw[f], (f32x4){0.f, 0.f, 0.f, 0.f}, 0, 0, 0);
                // pack 4 f32 -> 4 fp8 e4m3 in one dword (bytes s..s+3)
                int pk = __builtin_amdgcn_cvt_pk_fp8_f32(d[0] + biasv[f], d[1] + biasv[f], 0, false);
                pk     = __builtin_amdgcn_cvt_pk_fp8_f32(d[2] + biasv[f], d[3] + biasv[f], pk, true);
                int c = fh * 16 + lo;
                int s = q * 16 + hi * 4;
                *reinterpret_cast<int*>(trw + c * 72 + s) = pk;   // 2 lanes/bank: free
            }
        }
        asm volatile("" ::: "memory");   // fence: trw writes before reads
        char* outp = p ? b_t : a_t;
#pragma unroll
        for (int cg = 0; cg < 4; ++cg) {
            int c  = cg * 8 + (lane >> 3);
            int s8 = (lane & 7) * 8;
            i32x2 vv = *reinterpret_cast<const i32x2*>(trw + c * 72 + s8);
            // elem off = cg*512 + c_rel*64 + s8 = cg*512 + lane*8 -> 512B contiguous/instr
            *reinterpret_cast<i32x2*>(outp + wbase + cg * 512 + lane * 8) = vv;
        }
        asm volatile("" ::: "memory");   // fence: reads before p=1 overwrites
    }
}

// ---------------------------------------------------------------------------
// Pass 1 (unchanged v15/v16): fp8 GEMM. 64 independent GEMMs, 256x256 tiles,
// 8 waves, BK=32 dbuf. Rows are 32 B -> dense 512-B frag windows, no
// swizzle needed. mfma_f32_16x16x32_fp8_fp8. T1 XCD swizzle; epilogue
// folds 1/S, stores bf16.
// ---------------------------------------------------------------------------
__global__ __launch_bounds__(512, 2) void opm_gemm_kernel(
    const char* __restrict__ a_t,
    const char* __restrict__ b_t,
    __hip_bfloat16* __restrict__ outer)
{
    __shared__ __align__(16) char sA[2][GBM * BK];  // 8 KiB per buf
    __shared__ __align__(16) char sB[2][GBN * BK];  // total 32 KiB

    const int tid  = threadIdx.x;
    const int wave = tid >> 6;           // 0..7
    const int lane = tid & 63;
    // T1: 256 blocks % 8 == 0 -> bijective chunked swizzle (32 blocks/XCD)
    const int swz  = (blockIdx.x & 7) * 32 + (blockIdx.x >> 3);
    const int bc   = swz >> 2;           // (b*C + c), 0..63
    const int tile = swz & 3;            // 2x2 output tiles per GEMM
    const int i0   = (tile >> 1) * GBM;
    const int j0   = (tile & 1)  * GBN;

    const char* Ap = a_t + (size_t)(bc >> 5) * BST + (size_t)(bc & 31) * 64
                         + (size_t)(i0 >> 2) * IGST;
    const char* Bp = b_t + (size_t)(bc >> 5) * BST + (size_t)(bc & 31) * 64
                         + (size_t)(j0 >> 2) * IGST;

    f32x4 acc[8][4];
#pragma unroll
    for (int mI = 0; mI < 8; ++mI)
#pragma unroll
        for (int nI = 0; nI < 4; ++nI)
            acc[mI][nI] = (f32x4){0.f, 0.f, 0.f, 0.f};

    const int wr = wave >> 2;      // wave row (0..1): rows [wr*128, +128)
    const int wc = wave & 3;       // wave col (0..3): cols [wc*64, +64)
    const int half = lane >> 4;    // k-group (k = half*8 + e)
    const int lrow = lane & 15;

    // staging: thread -> (row = tid>>1, 16B-half = tid&1); LDS dest linear
    const int row_me = tid >> 1;                       // 0..255
    const size_t rowoff = (size_t)(row_me >> 2) * IGST + (size_t)(row_me & 3) * ILST
                        + (size_t)(tid & 1) * 16;

#define STAGE(bufidx, t) do {                                                              \
        const size_t sgo = (size_t)((t) >> 1) * SGST;                                      \
        const int    sho = ((t) & 1) * 32;                                                 \
        const char* gA0 = Ap + sgo + rowoff + sho;                                         \
        const char* gB0 = Bp + sgo + rowoff + sho;                                         \
        char* lA = (char*)(&sA[bufidx][0]) + tid * 16;                                     \
        char* lB = (char*)(&sB[bufidx][0]) + tid * 16;                                     \
        __builtin_amdgcn_global_load_lds((const __attribute__((address_space(1))) void*)gA0,      \
                                         (__attribute__((address_space(3))) void*)lA, 16, 0, 0);  \
        __builtin_amdgcn_global_load_lds((const __attribute__((address_space(1))) void*)gB0,      \
                                         (__attribute__((address_space(3))) void*)lB, 16, 0, 0);  \
    } while (0)

    STAGE(0, 0);
    asm volatile("s_waitcnt vmcnt(0)" ::: "memory");
    __syncthreads();

#pragma unroll 2
    for (int t = 0; t < NT; ++t) {
        const int cur = t & 1;
        if (t + 1 < NT) STAGE(cur ^ 1, t + 1);   // prefetch next K-slab

        const char* lA = &sA[cur][0];
        const char* lB = &sB[cur][0];
        long aF[8], bF[4];
#pragma unroll
        for (int mI = 0; mI < 8; ++mI) {
            int row = wr * 128 + mI * 16 + lrow;
            aF[mI] = *reinterpret_cast<const long*>(lA + row * 32 + half * 8);
        }
#pragma unroll
        for (int nI = 0; nI < 4; ++nI) {
            int row = wc * 64 + nI * 16 + lrow;
            bF[nI] = *reinterpret_cast<const long*>(lB + row * 32 + half * 8);
        }
#pragma unroll
        for (int mI = 0; mI < 8; ++mI)
#pragma unroll
            for (int nI = 0; nI < 4; ++nI)
                acc[mI][nI] = __builtin_amdgcn_mfma_f32_16x16x32_fp8_fp8(
                    aF[mI], bF[nI], acc[mI][nI], 0, 0, 0);

        __syncthreads();   // drains vmcnt+lgkmcnt (buffers safe to swap)
    }
#undef STAGE

    // C/D layout (dtype-independent): col = lane&15, row = (lane>>4)*4 + reg
    __hip_bfloat16* Op = outer + (size_t)bc * (I_ * I_);
#pragma unroll
    for (int mI = 0; mI < 8; ++mI) {
        int ii = i0 + wr * 128 + mI * 16 + half * 4;
#pragma unroll
        for (int nI = 0; nI < 4; ++nI) {
            int jj = j0 + wc * 64 + nI * 16 + lrow;
#pragma unroll
            for (int r = 0; r < 4; ++r)
                Op[(size_t)(ii + r) * I_ + jj] =
                    __float2bfloat16(acc[mI][nI][r] * (1.f / S_));
        }
    }
}

// ---------------------------------------------------------------------------
// Pass 2: out[b,i,j,c] = bo[c] + sum_c' Wo[c,c'] * outer_scaled[(b,c'),i,j]
// ---------------------------------------------------------------------------
__global__ __launch_bounds__(256) void wo_kernel(
    const __hip_bfloat16* __restrict__ outer,
    const float* __restrict__ Wo, const float* __restrict__ bo,
    float* __restrict__ out)
{
    int tid = blockIdx.x * 256 + threadIdx.x;   // ((b*I + i)*J + j)
    int j  = tid & (I_ - 1);
    int bi = tid >> 9;
    int i  = bi & (I_ - 1);
    int b  = bi >> 9;

    const __hip_bfloat16* ip = outer + ((size_t)(b * C_) * I_ + i) * I_ + j;
    float v[C_];
#pragma unroll
    for (int c = 0; c < C_; ++c) v[c] = __bfloat162float(ip[(size_t)c * (I_ * I_)]);

    float o[C_];
#pragma unroll
    for (int c = 0; c < C_; ++c) {
        float acc = bo[c];
#pragma unroll
        for (int k = 0; k < C_; ++k) acc = fmaf(Wo[c * C_ + k], v[k], acc);
        o[c] = acc;
    }

    float* op = out + (size_t)tid * C_;
#pragma unroll
    for (int vv = 0; vv < 8; ++vv) {
        float4 t4 = { o[4*vv+0], o[4*vv+1], o[4*vv+2], o[4*vv+3] };
        reinterpret_cast<float4*>(op)[vv] = t4;
    }
}

// ---------------------------------------------------------------------------
extern "C" void kernel_launch(void* const* d_in, const int* in_sizes, int n_in,
                              void* d_out, int out_size, void* d_ws, size_t ws_size,
                              hipStream_t stream) {
    const float* m    = (const float*)d_in[0];
    const float* ln_g = (const float*)d_in[1];
    const float* ln_b = (const float*)d_in[2];
    const float* Wa   = (const float*)d_in[3];
    const float* ba   = (const float*)d_in[4];
    const float* Wb   = (const float*)d_in[5];
    const float* bb   = (const float*)d_in[6];
    const float* Wo   = (const float*)d_in[7];
    const float* bo   = (const float*)d_in[8];
    float* out = (float*)d_out;

    const size_t ABYTES = (size_t)B_ * BST;          // fp8 bytes per array (~33.8 MB)
    const size_t nO  = (size_t)B_ * C_ * I_ * I_;    // outer elems (32 MiB bf16)
    const size_t need = ABYTES * 2 + nO * sizeof(__hip_bfloat16);  // ~100 MB
    if (ws_size < need) return;   // diagnostic: output stays zero -> ws too small

    char* a_t = (char*)d_ws;
    char* b_t = a_t + ABYTES;
    __hip_bfloat16* outer = (__hip_bfloat16*)(b_t + ABYTES);

    ln_proj_kernel<<<B_ * 16 * 128, 256, 0, stream>>>(m, ln_g, ln_b, Wa, ba, Wb, bb, a_t, b_t);
    opm_gemm_kernel<<<B_ * C_ * 4, 512, 0, stream>>>(a_t, b_t, outer);
    wo_kernel<<<(B_ * I_ * I_) / 256, 256, 0, stream>>>(outer, Wo, bo, out);
}